// Round 6
// baseline (27.681 us; speedup 1.0000x reference)
//
#include <hip/hip_runtime.h>
#include <math.h>
#include <stdint.h>

// Problem dims (fixed): B=8, C=128, M=16, H=W=128
#define NB 8
#define NC 128
#define NM 16
#define HW (128*128)        // 16384 positions
#define NOUTM 15
#define CH 8                // channels per block
#define NCT (NC / CH)       // 16 channel tiles
#define PCHUNK 8            // -> grid 8*16*8 = 1024 blocks = exactly 4/CU
#define POSC (HW / PCHUNK)  // 2048 positions per chunk
#define G2C (POSC / 2)      // 1024 float2-groups per chunk
#define NINF_PK 0xFC00FC00u // packed f16 {-inf,-inf}

__device__ __forceinline__ uint32_t pkmax(uint32_t a, uint32_t b) {
    uint32_t d;
    asm("v_pk_max_f16 %0, %1, %2" : "=v"(d) : "v"(a), "v"(b));
    return d;
}
__device__ __forceinline__ uint32_t bfi(uint32_t s, uint32_t a, uint32_t b) {
    uint32_t d;
    asm("v_bfi_b32 %0, %1, %2, %3" : "=v"(d) : "v"(s), "v"(a), "v"(b));
    return d;
}
__device__ __forceinline__ uint32_t cvt_dup(float f) {
    auto h = __builtin_amdgcn_cvt_pkrtz(f, f);   // monotone RTZ f32->f16 x2
    return __builtin_bit_cast(uint32_t, h);
}
__device__ __forceinline__ float h2f(uint32_t h16) {
    unsigned short u = (unsigned short)h16;
    __fp16 h = __builtin_bit_cast(__fp16, u);
    return (float)h;
}
// Exact f32 atomic max via CAS (values only grow from -inf).
__device__ __forceinline__ void atomicMaxF(float* addr, float val) {
    int* ia = (int*)addr;
    int cur = __float_as_int(-INFINITY);
    while (__int_as_float(cur) < val) {
        int prev = atomicCAS(ia, cur, __float_as_int(val));
        if (prev == cur) break;
        cur = prev;
    }
}

// ---------------------------------------------------------------------------
// Kernel 1: pack 15 mask planes into a bitmask per (b,pos), int2-vectorized;
// also initialize out[] to -inf (stream-ordered before kernel 2, re-runs
// every graph replay so the atomic-max output stays deterministic).
// ---------------------------------------------------------------------------
__global__ __launch_bounds__(256) void pack_masks_k(
        const int* __restrict__ masks, uint32_t* __restrict__ packed,
        float* __restrict__ out) {
    int idx = blockIdx.x * 256 + threadIdx.x;   // over NB*HW/2 = 65536
    int b  = idx >> 13;
    int p2 = idx & 8191;
    const int* mb = masks + (size_t)b * NM * HW + (size_t)p2 * 2;
    uint32_t b0 = 0, b1 = 0;
    #pragma unroll
    for (int m = 1; m < NM; ++m) {
        int2 mm = *(const int2*)(mb + (size_t)m * HW);
        uint32_t bit = 1u << (m - 1);
        if (mm.x) b0 |= bit;
        if (mm.y) b1 |= bit;
    }
    *(uint2*)(packed + (size_t)idx * 2) = make_uint2(b0, b1);
    if (idx < NB * NC * NOUTM) out[idx] = -INFINITY;
}

// ---------------------------------------------------------------------------
// Kernel 2: block=(chunk,ctile,b); 8 channels x 2048 positions.
// float2-grouped loads (9 x 8B per iter, 4 iters) keep peak live regs ~110
// so 4 blocks/CU fit (16 waves/CU).  Rotated traversal de-phases the
// power-of-2 stride bursts across blocks.  Packed-f16 acc, bfi+pk_max.
// 4-round LDS transpose reduce (17-pad, conflict-free), atomics into out.
// ---------------------------------------------------------------------------
#define DO_POS2(BW, C)                                                        \
    {                                                                         \
        uint32_t vv[8] = {cvt_dup(w0.C), cvt_dup(w1.C), cvt_dup(w2.C),        \
                          cvt_dup(w3.C), cvt_dup(w4.C), cvt_dup(w5.C),        \
                          cvt_dup(w6.C), cvt_dup(w7.C)};                      \
        uint32_t bw_ = (BW);                                                  \
        _Pragma("unroll") for (int mp = 0; mp < 8; ++mp) {                    \
            uint32_t lo = (uint32_t)((int32_t)(bw_ << (31 - 2 * mp)) >> 31);  \
            uint32_t hi = (uint32_t)((int32_t)(bw_ << (30 - 2 * mp)) >> 31);  \
            uint32_t s01 = __builtin_amdgcn_perm(hi, lo, 0x05040100u);        \
            _Pragma("unroll") for (int ch = 0; ch < 8; ++ch) {                \
                acc[ch * 8 + mp] =                                            \
                    pkmax(acc[ch * 8 + mp], bfi(s01, vv[ch], NINF_PK));       \
            }                                                                 \
        }                                                                     \
    }

__global__ __launch_bounds__(256, 4) void region_partial_k(
        const float* __restrict__ encoded,
        const uint32_t* __restrict__ packed,
        float* __restrict__ out) {
    int chunk = blockIdx.x;            // 0..PCHUNK-1
    int ctile = blockIdx.y;            // 0..NCT-1
    int b     = blockIdx.z;            // 0..NB-1
    int t     = threadIdx.x;

    const uint2*  bits2 = (const uint2*)(packed + (size_t)b * HW)
                          + (size_t)chunk * G2C;
    const float2* e2    = (const float2*)(encoded
                          + ((size_t)b * NC + (size_t)ctile * CH) * HW)
                          + (size_t)chunk * G2C;

    // per-block rotation: de-phase simultaneous power-of-2 stride bursts
    int rot = (ctile * 37 + chunk * 101 + b * 13) & (G2C - 1);

    uint32_t acc[64];
    #pragma unroll
    for (int w = 0; w < 64; ++w) acc[w] = NINF_PK;

    #pragma unroll 2
    for (int g = 0; g < G2C / 256; ++g) {       // 4 iterations
        int i = ((g * 256 + t) + rot) & (G2C - 1);
        uint2  bb = bits2[i];
        float2 w0 = e2[i + 0 * (HW / 2)];
        float2 w1 = e2[i + 1 * (HW / 2)];
        float2 w2 = e2[i + 2 * (HW / 2)];
        float2 w3 = e2[i + 3 * (HW / 2)];
        float2 w4 = e2[i + 4 * (HW / 2)];
        float2 w5 = e2[i + 5 * (HW / 2)];
        float2 w6 = e2[i + 6 * (HW / 2)];
        float2 w7 = e2[i + 7 * (HW / 2)];
        DO_POS2(bb.x, x)
        DO_POS2(bb.y, y)
    }

    // ---- 4-round x 16-word LDS transpose reduce (17-pad: conflict-free) ----
    __shared__ uint32_t ldsT[256 * 17];    // 17.4 KB
    __shared__ uint32_t lds2[256];
    __shared__ uint32_t finalw[64];

    #pragma unroll
    for (int r = 0; r < 4; ++r) {
        if (r) __syncthreads();
        #pragma unroll
        for (int j = 0; j < 16; ++j) ldsT[t * 17 + j] = acc[r * 16 + j];
        __syncthreads();
        int w = t & 15, s = t >> 4;        // 16 segments of 16 rows
        uint32_t v = ldsT[(s * 16) * 17 + w];
        #pragma unroll
        for (int k = 1; k < 16; ++k)
            v = pkmax(v, ldsT[(s * 16 + k) * 17 + w]);
        lds2[s * 16 + w] = v;
        __syncthreads();
        if (t < 16) {
            uint32_t rr = lds2[t];
            #pragma unroll
            for (int k = 1; k < 16; ++k) rr = pkmax(rr, lds2[k * 16 + t]);
            finalw[r * 16 + t] = rr;       // global word index = ch*8 + mp
        }
    }
    __syncthreads();

    // 120 valid outputs: ch in [0,8), m in [0,15)
    if (t < CH * NOUTM) {
        int ch = t / NOUTM, m = t % NOUTM;
        uint32_t wv = finalw[ch * 8 + (m >> 1)];
        float f = h2f((m & 1) ? (wv >> 16) : (wv & 0xFFFFu));
        int c = ctile * CH + ch;
        atomicMaxF(out + ((size_t)b * NC + c) * NOUTM + m, f);
    }
}

extern "C" void kernel_launch(void* const* d_in, const int* in_sizes, int n_in,
                              void* d_out, int out_size, void* d_ws, size_t ws_size,
                              hipStream_t stream) {
    const float* encoded = (const float*)d_in[0];   // [8,128,128,128] f32
    const int*   masks   = (const int*)d_in[1];     // [8,16,128,128] i32
    float*       out     = (float*)d_out;           // [8,128,15,1] f32

    uint32_t* packed = (uint32_t*)d_ws;             // 512 KB

    pack_masks_k<<<(NB * HW / 2) / 256, 256, 0, stream>>>(masks, packed, out);

    dim3 grid2(PCHUNK, NCT, NB);   // 8 x 16 x 8 = 1024 blocks = 4/CU, no tail
    region_partial_k<<<grid2, 256, 0, stream>>>(encoded, packed, out);
}

// Round 7
// 26.704 us; speedup vs baseline: 1.0366x; 1.0366x over previous
//
#include <hip/hip_runtime.h>
#include <math.h>
#include <stdint.h>

// Problem dims (fixed): B=8, C=128, M=16, H=W=128
#define NB 8
#define NC 128
#define NM 16
#define HW (128*128)        // 16384 positions
#define NOUTM 15
#define CH 8                // channels per block
#define NCT (NC / CH)       // 16 channel tiles
#define PCHUNK 8            // -> grid 8*16*8 = 1024 blocks = exactly 4/CU
#define F4C (HW / PCHUNK / 4)   // 512 float4-groups per chunk
#define NINF_PK 0xFC00FC00u // packed f16 {-inf,-inf}

__device__ __forceinline__ uint32_t pkmax(uint32_t a, uint32_t b) {
    uint32_t d;
    asm("v_pk_max_f16 %0, %1, %2" : "=v"(d) : "v"(a), "v"(b));
    return d;
}
__device__ __forceinline__ uint32_t bfi(uint32_t s, uint32_t a, uint32_t b) {
    uint32_t d;
    asm("v_bfi_b32 %0, %1, %2, %3" : "=v"(d) : "v"(s), "v"(a), "v"(b));
    return d;
}
__device__ __forceinline__ uint32_t cvt_dup(float f) {
    auto h = __builtin_amdgcn_cvt_pkrtz(f, f);   // monotone RTZ f32->f16 x2
    return __builtin_bit_cast(uint32_t, h);
}
__device__ __forceinline__ float h2f(uint32_t h16) {
    unsigned short u = (unsigned short)h16;
    __fp16 h = __builtin_bit_cast(__fp16, u);
    return (float)h;
}
// Exact f32 atomic max via CAS (values only grow from -inf).
__device__ __forceinline__ void atomicMaxF(float* addr, float val) {
    int* ia = (int*)addr;
    int cur = __float_as_int(-INFINITY);
    while (__int_as_float(cur) < val) {
        int prev = atomicCAS(ia, cur, __float_as_int(val));
        if (prev == cur) break;
        cur = prev;
    }
}

// ---------------------------------------------------------------------------
// Kernel 1: pack 15 mask planes into a bitmask per (b,pos).
// int4 (16B) loads; planes split 4-way across thread groups (4/4/4/3),
// partial bitmasks OR-combined through LDS.  512 blocks x 256 thr =
// 2 blocks/CU, 8 waves/CU.  masks are 0/1 so bit = value (lshl_or, no cmp).
// Also initializes out[] to -inf (stream-ordered before kernel 2; re-runs
// every replay so atomic-max output stays deterministic).
// ---------------------------------------------------------------------------
__global__ __launch_bounds__(256) void pack_masks_k(
        const int* __restrict__ masks, uint32_t* __restrict__ packed,
        float* __restrict__ out) {
    int t    = threadIdx.x;
    int gid  = blockIdx.x * 64 + (t & 63);   // int4-group id, 0..32767
    int pset = t >> 6;                        // 0..3 -> planes 4/4/4/3
    int b    = gid >> 12;                     // 4096 groups per batch
    int p4   = gid & 4095;
    const int* mb = masks + (size_t)b * NM * HW + (size_t)p4 * 4;

    uint32_t b0 = 0, b1 = 0, b2 = 0, b3 = 0;
    int mlo = pset * 4 + 1;
    int mhi = (pset == 3) ? 15 : (mlo + 3);   // inclusive
    #pragma unroll
    for (int m = 1; m < NM; ++m) {
        if (m >= mlo && m <= mhi) {
            int4 mm = *(const int4*)(mb + (size_t)m * HW);
            int sh = m - 1;
            b0 |= ((uint32_t)mm.x) << sh;     // mask values are 0/1
            b1 |= ((uint32_t)mm.y) << sh;
            b2 |= ((uint32_t)mm.z) << sh;
            b3 |= ((uint32_t)mm.w) << sh;
        }
    }

    __shared__ uint4 lds[4][64];
    lds[pset][t & 63] = make_uint4(b0, b1, b2, b3);
    __syncthreads();
    if (t < 64) {
        uint4 a = lds[0][t], c = lds[1][t], d = lds[2][t], e = lds[3][t];
        uint4 r = make_uint4(a.x | c.x | d.x | e.x,
                             a.y | c.y | d.y | e.y,
                             a.z | c.z | d.z | e.z,
                             a.w | c.w | d.w | e.w);
        *(uint4*)(packed + (size_t)gid * 4) = r;
    }

    int flat = blockIdx.x * 256 + t;
    if (flat < NB * NC * NOUTM) out[flat] = -INFINITY;
}

// ---------------------------------------------------------------------------
// Kernel 2: block=(chunk,ctile,b); 8 channels x 2048 positions.
// float4 loads (9 x 16B per iter, 2 iters) -> ~18KB/wave in flight.
// Packed-f16 acc, perm+bfi select, pk_max.  4-round LDS transpose reduce
// (17-pad, conflict-free), f32 CAS atomic-max into out.
// ---------------------------------------------------------------------------
#define DO_POS(BW, C)                                                         \
    {                                                                         \
        uint32_t vv[8] = {cvt_dup(v0.C), cvt_dup(v1.C), cvt_dup(v2.C),        \
                          cvt_dup(v3.C), cvt_dup(v4.C), cvt_dup(v5.C),        \
                          cvt_dup(v6.C), cvt_dup(v7.C)};                      \
        uint32_t bw_ = (BW);                                                  \
        _Pragma("unroll") for (int mp = 0; mp < 8; ++mp) {                    \
            uint32_t lo = (uint32_t)((int32_t)(bw_ << (31 - 2 * mp)) >> 31);  \
            uint32_t hi = (uint32_t)((int32_t)(bw_ << (30 - 2 * mp)) >> 31);  \
            uint32_t s01 = __builtin_amdgcn_perm(hi, lo, 0x05040100u);        \
            _Pragma("unroll") for (int ch = 0; ch < 8; ++ch) {                \
                acc[ch * 8 + mp] =                                            \
                    pkmax(acc[ch * 8 + mp], bfi(s01, vv[ch], NINF_PK));       \
            }                                                                 \
        }                                                                     \
    }

__global__ __launch_bounds__(256, 4) void region_partial_k(
        const float* __restrict__ encoded,
        const uint32_t* __restrict__ packed,
        float* __restrict__ out) {
    int chunk = blockIdx.x;            // 0..PCHUNK-1
    int ctile = blockIdx.y;            // 0..NCT-1
    int b     = blockIdx.z;            // 0..NB-1
    int t     = threadIdx.x;

    const uint4*  bits4 = (const uint4*)(packed + (size_t)b * HW)
                          + (size_t)chunk * F4C;
    const float4* e4    = (const float4*)(encoded
                          + ((size_t)b * NC + (size_t)ctile * CH) * HW)
                          + (size_t)chunk * F4C;

    uint32_t acc[64];
    #pragma unroll
    for (int w = 0; w < 64; ++w) acc[w] = NINF_PK;

    #pragma unroll
    for (int g = 0; g < F4C / 256; ++g) {       // 2 iterations
        int i = g * 256 + t;
        uint4  bb = bits4[i];
        float4 v0 = e4[i + 0 * (HW / 4)];
        float4 v1 = e4[i + 1 * (HW / 4)];
        float4 v2 = e4[i + 2 * (HW / 4)];
        float4 v3 = e4[i + 3 * (HW / 4)];
        float4 v4 = e4[i + 4 * (HW / 4)];
        float4 v5 = e4[i + 5 * (HW / 4)];
        float4 v6 = e4[i + 6 * (HW / 4)];
        float4 v7 = e4[i + 7 * (HW / 4)];
        DO_POS(bb.x, x)
        DO_POS(bb.y, y)
        DO_POS(bb.z, z)
        DO_POS(bb.w, w)
    }

    // ---- 4-round x 16-word LDS transpose reduce (17-pad: conflict-free) ----
    __shared__ uint32_t ldsT[256 * 17];    // 17.4 KB (x4 blocks = 70 KB/CU)
    __shared__ uint32_t lds2[256];
    __shared__ uint32_t finalw[64];

    #pragma unroll
    for (int r = 0; r < 4; ++r) {
        if (r) __syncthreads();
        #pragma unroll
        for (int j = 0; j < 16; ++j) ldsT[t * 17 + j] = acc[r * 16 + j];
        __syncthreads();
        int w = t & 15, s = t >> 4;        // 16 segments of 16 rows
        uint32_t v = ldsT[(s * 16) * 17 + w];
        #pragma unroll
        for (int k = 1; k < 16; ++k)
            v = pkmax(v, ldsT[(s * 16 + k) * 17 + w]);
        lds2[s * 16 + w] = v;
        __syncthreads();
        if (t < 16) {
            uint32_t rr = lds2[t];
            #pragma unroll
            for (int k = 1; k < 16; ++k) rr = pkmax(rr, lds2[k * 16 + t]);
            finalw[r * 16 + t] = rr;       // global word index = ch*8 + mp
        }
    }
    __syncthreads();

    // 120 valid outputs: ch in [0,8), m in [0,15)
    if (t < CH * NOUTM) {
        int ch = t / NOUTM, m = t % NOUTM;
        uint32_t wv = finalw[ch * 8 + (m >> 1)];
        float f = h2f((m & 1) ? (wv >> 16) : (wv & 0xFFFFu));
        int c = ctile * CH + ch;
        atomicMaxF(out + ((size_t)b * NC + c) * NOUTM + m, f);
    }
}

extern "C" void kernel_launch(void* const* d_in, const int* in_sizes, int n_in,
                              void* d_out, int out_size, void* d_ws, size_t ws_size,
                              hipStream_t stream) {
    const float* encoded = (const float*)d_in[0];   // [8,128,128,128] f32
    const int*   masks   = (const int*)d_in[1];     // [8,16,128,128] i32
    float*       out     = (float*)d_out;           // [8,128,15,1] f32

    uint32_t* packed = (uint32_t*)d_ws;             // 512 KB

    pack_masks_k<<<512, 256, 0, stream>>>(masks, packed, out);

    dim3 grid2(PCHUNK, NCT, NB);   // 8 x 16 x 8 = 1024 blocks = 4/CU, no tail
    region_partial_k<<<grid2, 256, 0, stream>>>(encoded, packed, out);
}